// Round 1
// baseline (7647.071 us; speedup 1.0000x reference)
//
#include <hip/hip_runtime.h>
#include <hip/hip_fp16.h>

namespace {

constexpr int NB = 16;
constexpr int MM = 2048;
constexpr int NN = 2048;
constexpr float NEG_INV_EPS = -10.0f;   // -1/epsilon, epsilon = 0.1
constexpr int ITERS = 100;

// ---- K-source abstraction: fp16 staged kernel matrix, or recompute from C ----

struct KHalf {
  const __half* p;
  __device__ __forceinline__ void load8(size_t i, float* o) const {
    uint4 v = *reinterpret_cast<const uint4*>(p + i);
    const __half2* h = reinterpret_cast<const __half2*>(&v);
    float2 f0 = __half22float2(h[0]);
    float2 f1 = __half22float2(h[1]);
    float2 f2 = __half22float2(h[2]);
    float2 f3 = __half22float2(h[3]);
    o[0] = f0.x; o[1] = f0.y; o[2] = f1.x; o[3] = f1.y;
    o[4] = f2.x; o[5] = f2.y; o[6] = f3.x; o[7] = f3.y;
  }
};

struct KFromC {
  const float* p;
  __device__ __forceinline__ void load8(size_t i, float* o) const {
    float4 c0 = *reinterpret_cast<const float4*>(p + i);
    float4 c1 = *reinterpret_cast<const float4*>(p + i + 4);
    o[0] = __expf(NEG_INV_EPS * c0.x); o[1] = __expf(NEG_INV_EPS * c0.y);
    o[2] = __expf(NEG_INV_EPS * c0.z); o[3] = __expf(NEG_INV_EPS * c0.w);
    o[4] = __expf(NEG_INV_EPS * c1.x); o[5] = __expf(NEG_INV_EPS * c1.y);
    o[6] = __expf(NEG_INV_EPS * c1.z); o[7] = __expf(NEG_INV_EPS * c1.w);
  }
};

// ---- Stage K = exp(-C/eps) as fp16 ----

__global__ void __launch_bounds__(256) build_k(const float* __restrict__ C,
                                               __half* __restrict__ K) {
  const size_t stride = (size_t)gridDim.x * blockDim.x * 8;
  const size_t total = (size_t)NB * MM * NN;
  for (size_t i = ((size_t)blockIdx.x * blockDim.x + threadIdx.x) * 8;
       i < total; i += stride) {
    float4 c0 = *reinterpret_cast<const float4*>(C + i);
    float4 c1 = *reinterpret_cast<const float4*>(C + i + 4);
    __half2 h[4];
    h[0] = __floats2half2_rn(__expf(NEG_INV_EPS * c0.x), __expf(NEG_INV_EPS * c0.y));
    h[1] = __floats2half2_rn(__expf(NEG_INV_EPS * c0.z), __expf(NEG_INV_EPS * c0.w));
    h[2] = __floats2half2_rn(__expf(NEG_INV_EPS * c1.x), __expf(NEG_INV_EPS * c1.y));
    h[3] = __floats2half2_rn(__expf(NEG_INV_EPS * c1.z), __expf(NEG_INV_EPS * c1.w));
    *reinterpret_cast<uint4*>(K + i) = *reinterpret_cast<uint4*>(h);
  }
}

// ---- Row pass: w = b / s_cur (computed per block), r = K @ w, z = a / r.
//      Also zeroes s_next so the following col pass can accumulate into it. ----
// grid = NB*512 blocks, 256 threads (4 waves), 1 row per wave.

template <class KS>
__global__ void __launch_bounds__(256) row_pass(KS ks,
    const float* __restrict__ a, const float* __restrict__ bm,
    const float* __restrict__ s_cur, float* __restrict__ s_next,
    float* __restrict__ z) {
  __shared__ __align__(16) float wsh[NN];
  const int b = blockIdx.x >> 9;        // / 512
  const int local = blockIdx.x & 511;
  const int tid = threadIdx.x;
  const int bbase = b * NN;

  for (int j = tid; j < NN; j += 256)
    wsh[j] = bm[bbase + j] / s_cur[bbase + j];
  if (tid < 4) s_next[bbase + local * 4 + tid] = 0.0f;
  __syncthreads();

  const int wave = tid >> 6;
  const int lane = tid & 63;
  const int row = local * 4 + wave;
  const size_t kbase = ((size_t)(b * MM + row)) * NN;

  float acc = 0.0f;
#pragma unroll
  for (int k = 0; k < 4; ++k) {
    const int j = k * 512 + lane * 8;
    float kv[8];
    ks.load8(kbase + j, kv);
    const float4* w4 = reinterpret_cast<const float4*>(&wsh[j]);
    float4 wa = w4[0], wb = w4[1];
    acc += kv[0] * wa.x + kv[1] * wa.y + kv[2] * wa.z + kv[3] * wa.w +
           kv[4] * wb.x + kv[5] * wb.y + kv[6] * wb.z + kv[7] * wb.w;
  }
#pragma unroll
  for (int off = 32; off; off >>= 1) acc += __shfl_xor(acc, off, 64);
  if (lane == 0) {
    const int g = bbase + row;
    z[g] = a[g] / acc;
  }
}

// ---- Col pass: s_next += K^T @ z (partial over a 64-row chunk, atomics). ----
// grid = NB*32 blocks, 256 threads, 8 consecutive cols per thread (full 2048 width).

template <class KS>
__global__ void __launch_bounds__(256) col_pass(KS ks,
    const float* __restrict__ z, float* __restrict__ s_next) {
  __shared__ float zsh[64];
  const int b = blockIdx.x >> 5;        // / 32
  const int chunk = blockIdx.x & 31;
  const int tid = threadIdx.x;
  const int r0 = chunk * 64;
  if (tid < 64) zsh[tid] = z[b * MM + r0 + tid];
  __syncthreads();

  const int col = tid * 8;
  float acc[8] = {0, 0, 0, 0, 0, 0, 0, 0};
#pragma unroll 4
  for (int r = 0; r < 64; ++r) {
    const float zi = zsh[r];
    float kv[8];
    ks.load8(((size_t)(b * MM + r0 + r)) * NN + col, kv);
#pragma unroll
    for (int m = 0; m < 8; ++m) acc[m] += kv[m] * zi;
  }
  float* s = s_next + b * NN + col;
#pragma unroll
  for (int m = 0; m < 8; ++m) atomicAdd(&s[m], acc[m]);
}

// ---- Final: P = z_i * exp(-C/eps) * w_j (exact C), dist = sum(P*C). ----
// grid = NB*128 blocks (16 rows each), 256 threads, 8 cols per thread.

__global__ void __launch_bounds__(256) final_pass(const float* __restrict__ C,
    const float* __restrict__ z, const float* __restrict__ bm,
    const float* __restrict__ s_fin, float* __restrict__ out) {
  __shared__ __align__(16) float wsh[NN];
  __shared__ float zsh[16];
  __shared__ float red[256];
  const int b = blockIdx.x >> 7;        // / 128
  const int rc = blockIdx.x & 127;
  const int tid = threadIdx.x;
  const int bbase = b * NN;

  for (int j = tid; j < NN; j += 256)
    wsh[j] = bm[bbase + j] / s_fin[bbase + j];
  if (tid < 16) zsh[tid] = z[b * MM + rc * 16 + tid];
  __syncthreads();

  float* __restrict__ P = out + NB;
  const int col = tid * 8;
  const float4* w4 = reinterpret_cast<const float4*>(&wsh[col]);
  const float4 wa = w4[0], wb = w4[1];

  float accd = 0.0f;
#pragma unroll 4
  for (int rr = 0; rr < 16; ++rr) {
    const int row = rc * 16 + rr;
    const float zi = zsh[rr];
    const size_t base = ((size_t)(b * MM + row)) * NN + col;
    float4 c0 = *reinterpret_cast<const float4*>(C + base);
    float4 c1 = *reinterpret_cast<const float4*>(C + base + 4);
    float4 p0, p1;
    p0.x = zi * __expf(NEG_INV_EPS * c0.x) * wa.x;
    p0.y = zi * __expf(NEG_INV_EPS * c0.y) * wa.y;
    p0.z = zi * __expf(NEG_INV_EPS * c0.z) * wa.z;
    p0.w = zi * __expf(NEG_INV_EPS * c0.w) * wa.w;
    p1.x = zi * __expf(NEG_INV_EPS * c1.x) * wb.x;
    p1.y = zi * __expf(NEG_INV_EPS * c1.y) * wb.y;
    p1.z = zi * __expf(NEG_INV_EPS * c1.z) * wb.z;
    p1.w = zi * __expf(NEG_INV_EPS * c1.w) * wb.w;
    *reinterpret_cast<float4*>(P + base) = p0;
    *reinterpret_cast<float4*>(P + base + 4) = p1;
    accd += p0.x * c0.x + p0.y * c0.y + p0.z * c0.z + p0.w * c0.w +
            p1.x * c1.x + p1.y * c1.y + p1.z * c1.z + p1.w * c1.w;
  }

  red[tid] = accd;
  __syncthreads();
  if (tid < 128) red[tid] += red[tid + 128];
  __syncthreads();
  if (tid < 64) {
    float v = red[tid] + red[tid + 64];
#pragma unroll
    for (int off = 32; off; off >>= 1) v += __shfl_xor(v, off, 64);
    if (tid == 0) atomicAdd(&out[b], v);
  }
}

}  // namespace

extern "C" void kernel_launch(void* const* d_in, const int* in_sizes, int n_in,
                              void* d_out, int out_size, void* d_ws, size_t ws_size,
                              hipStream_t stream) {
  const float* C  = (const float*)d_in[0];
  const float* a  = (const float*)d_in[1];
  const float* bm = (const float*)d_in[2];
  float* out = (float*)d_out;
  char* ws = (char*)d_ws;

  const size_t VEC = (size_t)NB * MM * sizeof(float);       // 131072 B
  float* z  = (float*)(ws);
  float* s0 = (float*)(ws + VEC);
  float* s1 = (float*)(ws + 2 * VEC);
  __half* K = (__half*)(ws + 3 * VEC);
  const size_t needK = 3 * VEC + (size_t)NB * MM * NN * sizeof(__half);
  const bool useHalf = (ws_size >= needK);

  hipMemsetAsync(out, 0, NB * sizeof(float), stream);
  // s0 = b  =>  first row pass sees w = b/s0 = 1 (i.e. v0 = 0)
  hipMemcpyAsync(s0, bm, (size_t)NB * NN * sizeof(float),
                 hipMemcpyDeviceToDevice, stream);

  float* cur = s0;
  float* nxt = s1;

  if (useHalf) {
    build_k<<<8192, 256, 0, stream>>>(C, K);
    KHalf ks{K};
    for (int t = 0; t < ITERS; ++t) {
      row_pass<KHalf><<<NB * 512, 256, 0, stream>>>(ks, a, bm, cur, nxt, z);
      col_pass<KHalf><<<NB * 32, 256, 0, stream>>>(ks, z, nxt);
      float* tmp = cur; cur = nxt; nxt = tmp;
    }
  } else {
    KFromC ks{C};
    for (int t = 0; t < ITERS; ++t) {
      row_pass<KFromC><<<NB * 512, 256, 0, stream>>>(ks, a, bm, cur, nxt, z);
      col_pass<KFromC><<<NB * 32, 256, 0, stream>>>(ks, z, nxt);
      float* tmp = cur; cur = nxt; nxt = tmp;
    }
  }

  final_pass<<<NB * 128, 256, 0, stream>>>(C, z, bm, cur, out);
}

// Round 2
// 4460.575 us; speedup vs baseline: 1.7144x; 1.7144x over previous
//
#include <hip/hip_runtime.h>
#include <hip/hip_fp16.h>

namespace {

constexpr int NB = 16;
constexpr int MM = 2048;
constexpr int NN = 2048;
constexpr float NEG_INV_EPS = -10.0f;   // -1/epsilon, epsilon = 0.1
constexpr int ITERS = 100;

// ---- K-source abstraction: fp16 staged kernel matrix, or recompute from C ----

struct KHalf {
  const __half* p;
  __device__ __forceinline__ void load8(size_t i, float* o) const {
    uint4 v = *reinterpret_cast<const uint4*>(p + i);
    const __half2* h = reinterpret_cast<const __half2*>(&v);
    float2 f0 = __half22float2(h[0]);
    float2 f1 = __half22float2(h[1]);
    float2 f2 = __half22float2(h[2]);
    float2 f3 = __half22float2(h[3]);
    o[0] = f0.x; o[1] = f0.y; o[2] = f1.x; o[3] = f1.y;
    o[4] = f2.x; o[5] = f2.y; o[6] = f3.x; o[7] = f3.y;
  }
  __device__ __forceinline__ void load4(size_t i, float* o) const {
    uint2 v = *reinterpret_cast<const uint2*>(p + i);
    const __half2* h = reinterpret_cast<const __half2*>(&v);
    float2 f0 = __half22float2(h[0]);
    float2 f1 = __half22float2(h[1]);
    o[0] = f0.x; o[1] = f0.y; o[2] = f1.x; o[3] = f1.y;
  }
};

struct KFromC {
  const float* p;
  __device__ __forceinline__ void load8(size_t i, float* o) const {
    float4 c0 = *reinterpret_cast<const float4*>(p + i);
    float4 c1 = *reinterpret_cast<const float4*>(p + i + 4);
    o[0] = __expf(NEG_INV_EPS * c0.x); o[1] = __expf(NEG_INV_EPS * c0.y);
    o[2] = __expf(NEG_INV_EPS * c0.z); o[3] = __expf(NEG_INV_EPS * c0.w);
    o[4] = __expf(NEG_INV_EPS * c1.x); o[5] = __expf(NEG_INV_EPS * c1.y);
    o[6] = __expf(NEG_INV_EPS * c1.z); o[7] = __expf(NEG_INV_EPS * c1.w);
  }
  __device__ __forceinline__ void load4(size_t i, float* o) const {
    float4 c0 = *reinterpret_cast<const float4*>(p + i);
    o[0] = __expf(NEG_INV_EPS * c0.x); o[1] = __expf(NEG_INV_EPS * c0.y);
    o[2] = __expf(NEG_INV_EPS * c0.z); o[3] = __expf(NEG_INV_EPS * c0.w);
  }
};

// ---- Stage K = exp(-C/eps) as fp16 ----

__global__ void __launch_bounds__(256) build_k(const float* __restrict__ C,
                                               __half* __restrict__ K) {
  const size_t stride = (size_t)gridDim.x * blockDim.x * 8;
  const size_t total = (size_t)NB * MM * NN;
  for (size_t i = ((size_t)blockIdx.x * blockDim.x + threadIdx.x) * 8;
       i < total; i += stride) {
    float4 c0 = *reinterpret_cast<const float4*>(C + i);
    float4 c1 = *reinterpret_cast<const float4*>(C + i + 4);
    __half2 h[4];
    h[0] = __floats2half2_rn(__expf(NEG_INV_EPS * c0.x), __expf(NEG_INV_EPS * c0.y));
    h[1] = __floats2half2_rn(__expf(NEG_INV_EPS * c0.z), __expf(NEG_INV_EPS * c0.w));
    h[2] = __floats2half2_rn(__expf(NEG_INV_EPS * c1.x), __expf(NEG_INV_EPS * c1.y));
    h[3] = __floats2half2_rn(__expf(NEG_INV_EPS * c1.z), __expf(NEG_INV_EPS * c1.w));
    *reinterpret_cast<uint4*>(K + i) = *reinterpret_cast<uint4*>(h);
  }
}

// ---- Fused Sinkhorn iteration ----
// grid = NB*32 blocks (one 64-row chunk each), 512 threads (8 waves).
// Buffer rotation: read s_cur, atomicAdd into s_acc, zero s_zero.
// Phase 1 (per 16-row sub-chunk): 8 waves x 2 rows, full-row dot with w in
//   registers -> z.  Phase 2: re-read the same 16 rows (L2-hot), accumulate
//   column partials in registers.  One atomic sweep per block at the end.

template <class KS>
__global__ void __launch_bounds__(512, 4) sink_iter(KS ks,
    const float* __restrict__ a, const float* __restrict__ bm,
    const float* __restrict__ s_cur, float* __restrict__ s_acc,
    float* __restrict__ s_zero, float* __restrict__ z_out) {
  __shared__ __align__(16) float wsh[NN];
  __shared__ float zsh[16];
  const int b = blockIdx.x >> 5;
  const int chunk = blockIdx.x & 31;
  const int tid = threadIdx.x;
  const int bbase = b * NN;

  {  // cooperative w = b * rcp(s) into LDS, vectorized (512 thr x float4)
    const float4 b4 = *reinterpret_cast<const float4*>(bm + bbase + tid * 4);
    const float4 s4 = *reinterpret_cast<const float4*>(s_cur + bbase + tid * 4);
    float4 w4;
    w4.x = b4.x * __builtin_amdgcn_rcpf(s4.x);
    w4.y = b4.y * __builtin_amdgcn_rcpf(s4.y);
    w4.z = b4.z * __builtin_amdgcn_rcpf(s4.z);
    w4.w = b4.w * __builtin_amdgcn_rcpf(s4.w);
    *reinterpret_cast<float4*>(&wsh[tid * 4]) = w4;
  }
  if (tid < 64) s_zero[bbase + chunk * 64 + tid] = 0.0f;
  __syncthreads();

  const int wave = tid >> 6;
  const int lane = tid & 63;

  // per-lane w fragment (32 floats), reused for every row this wave processes
  float wreg[32];
#pragma unroll
  for (int k = 0; k < 4; ++k) {
    const float4* w4 = reinterpret_cast<const float4*>(&wsh[k * 512 + lane * 8]);
    const float4 wa = w4[0], wb = w4[1];
    wreg[k * 8 + 0] = wa.x; wreg[k * 8 + 1] = wa.y;
    wreg[k * 8 + 2] = wa.z; wreg[k * 8 + 3] = wa.w;
    wreg[k * 8 + 4] = wb.x; wreg[k * 8 + 5] = wb.y;
    wreg[k * 8 + 6] = wb.z; wreg[k * 8 + 7] = wb.w;
  }

  const int r0 = chunk * 64;
  const int mycol = tid * 4;
  float colacc[4] = {0.f, 0.f, 0.f, 0.f};

  for (int sc = 0; sc < 4; ++sc) {
    const int rowbase = r0 + sc * 16;
    // ---- phase 1: row dots for 16 rows (8 waves x 2 rows) ----
#pragma unroll
    for (int rr = 0; rr < 2; ++rr) {
      const int row = rowbase + wave * 2 + rr;
      const size_t kb = ((size_t)(b * MM + row)) * NN;
      float acc = 0.f;
#pragma unroll
      for (int k = 0; k < 4; ++k) {
        float kv[8];
        ks.load8(kb + k * 512 + lane * 8, kv);
#pragma unroll
        for (int m = 0; m < 8; ++m) acc += kv[m] * wreg[k * 8 + m];
      }
#pragma unroll
      for (int off = 32; off; off >>= 1) acc += __shfl_xor(acc, off, 64);
      if (lane == 0) {
        const float zv = a[b * MM + row] * __builtin_amdgcn_rcpf(acc);
        zsh[wave * 2 + rr] = zv;
        z_out[b * MM + row] = zv;
      }
    }
    __syncthreads();
    // ---- phase 2: column partials over the same 16 rows (L2-hot) ----
#pragma unroll 4
    for (int r = 0; r < 16; ++r) {
      const float zi = zsh[r];
      float kv[4];
      ks.load4(((size_t)(b * MM + rowbase + r)) * NN + mycol, kv);
#pragma unroll
      for (int m = 0; m < 4; ++m) colacc[m] += kv[m] * zi;
    }
    __syncthreads();
  }

  float* s = s_acc + bbase + mycol;
#pragma unroll
  for (int m = 0; m < 4; ++m) atomicAdd(&s[m], colacc[m]);
}

// ---- Final: P = z_i * exp(-C/eps) * w_j (exact C), dist = sum(P*C). ----
// grid = NB*128 blocks (16 rows each), 256 threads, 8 cols per thread.

__global__ void __launch_bounds__(256) final_pass(const float* __restrict__ C,
    const float* __restrict__ z, const float* __restrict__ bm,
    const float* __restrict__ s_fin, float* __restrict__ out) {
  __shared__ __align__(16) float wsh[NN];
  __shared__ float zsh[16];
  __shared__ float red[256];
  const int b = blockIdx.x >> 7;        // / 128
  const int rc = blockIdx.x & 127;
  const int tid = threadIdx.x;
  const int bbase = b * NN;

  for (int j = tid; j < NN; j += 256)
    wsh[j] = bm[bbase + j] * __builtin_amdgcn_rcpf(s_fin[bbase + j]);
  if (tid < 16) zsh[tid] = z[b * MM + rc * 16 + tid];
  __syncthreads();

  float* __restrict__ P = out + NB;
  const int col = tid * 8;
  const float4* w4 = reinterpret_cast<const float4*>(&wsh[col]);
  const float4 wa = w4[0], wb = w4[1];

  float accd = 0.0f;
#pragma unroll 4
  for (int rr = 0; rr < 16; ++rr) {
    const int row = rc * 16 + rr;
    const float zi = zsh[rr];
    const size_t base = ((size_t)(b * MM + row)) * NN + col;
    float4 c0 = *reinterpret_cast<const float4*>(C + base);
    float4 c1 = *reinterpret_cast<const float4*>(C + base + 4);
    float4 p0, p1;
    p0.x = zi * __expf(NEG_INV_EPS * c0.x) * wa.x;
    p0.y = zi * __expf(NEG_INV_EPS * c0.y) * wa.y;
    p0.z = zi * __expf(NEG_INV_EPS * c0.z) * wa.z;
    p0.w = zi * __expf(NEG_INV_EPS * c0.w) * wa.w;
    p1.x = zi * __expf(NEG_INV_EPS * c1.x) * wb.x;
    p1.y = zi * __expf(NEG_INV_EPS * c1.y) * wb.y;
    p1.z = zi * __expf(NEG_INV_EPS * c1.z) * wb.z;
    p1.w = zi * __expf(NEG_INV_EPS * c1.w) * wb.w;
    *reinterpret_cast<float4*>(P + base) = p0;
    *reinterpret_cast<float4*>(P + base + 4) = p1;
    accd += p0.x * c0.x + p0.y * c0.y + p0.z * c0.z + p0.w * c0.w +
            p1.x * c1.x + p1.y * c1.y + p1.z * c1.z + p1.w * c1.w;
  }

  red[tid] = accd;
  __syncthreads();
  if (tid < 128) red[tid] += red[tid + 128];
  __syncthreads();
  if (tid < 64) {
    float v = red[tid] + red[tid + 64];
#pragma unroll
    for (int off = 32; off; off >>= 1) v += __shfl_xor(v, off, 64);
    if (tid == 0) atomicAdd(&out[b], v);
  }
}

}  // namespace

extern "C" void kernel_launch(void* const* d_in, const int* in_sizes, int n_in,
                              void* d_out, int out_size, void* d_ws, size_t ws_size,
                              hipStream_t stream) {
  const float* C  = (const float*)d_in[0];
  const float* a  = (const float*)d_in[1];
  const float* bm = (const float*)d_in[2];
  float* out = (float*)d_out;
  char* ws = (char*)d_ws;

  const size_t VEC = (size_t)NB * MM * sizeof(float);       // 131072 B
  float* z = (float*)(ws);
  float* s[3] = {(float*)(ws + VEC), (float*)(ws + 2 * VEC), (float*)(ws + 3 * VEC)};
  __half* K = (__half*)(ws + 4 * VEC);
  const size_t needK = 4 * VEC + (size_t)NB * MM * NN * sizeof(__half);
  const bool useHalf = (ws_size >= needK);

  hipMemsetAsync(out, 0, NB * sizeof(float), stream);
  // s[0] = b  =>  first iteration sees w = b/s = 1 (i.e. v0 = 0)
  hipMemcpyAsync(s[0], bm, (size_t)NB * NN * sizeof(float),
                 hipMemcpyDeviceToDevice, stream);
  // iter 0 accumulates into s[1]; s[2] is zeroed by iter 0 itself
  hipMemsetAsync(s[1], 0, (size_t)NB * NN * sizeof(float), stream);

  if (useHalf) {
    build_k<<<8192, 256, 0, stream>>>(C, K);
    KHalf ks{K};
    for (int t = 0; t < ITERS; ++t) {
      sink_iter<KHalf><<<NB * 32, 512, 0, stream>>>(
          ks, a, bm, s[t % 3], s[(t + 1) % 3], s[(t + 2) % 3], z);
    }
  } else {
    KFromC ks{C};
    for (int t = 0; t < ITERS; ++t) {
      sink_iter<KFromC><<<NB * 32, 512, 0, stream>>>(
          ks, a, bm, s[t % 3], s[(t + 1) % 3], s[(t + 2) % 3], z);
    }
  }

  final_pass<<<NB * 128, 256, 0, stream>>>(C, z, bm, s[ITERS % 3], out);
}